// Round 10
// baseline (81.608 us; speedup 1.0000x reference)
//
#include <hip/hip_runtime.h>
#include <hip/hip_bf16.h>
#include <cstddef>

#define T_DIM 2048
#define D_DIM 1024
#define GAMMA_F 0.96875f

typedef __attribute__((ext_vector_type(8))) short bf16x8;
typedef __attribute__((ext_vector_type(8))) ushort ushortx8;
typedef __attribute__((ext_vector_type(4))) float f32x4;

#define AS1 __attribute__((address_space(1)))
#define AS3 __attribute__((address_space(3)))

static __device__ inline ushort f2bs(float f) {
    __hip_bfloat16 h = __float2bfloat16(f);
    return *reinterpret_cast<ushort*>(&h);
}

// Exhaustive + fail-closed: an unmatched N is a COMPILE ERROR, never a no-op.
// (Round-9 bug: vm_wait<3> silently compiled to nothing -> missing wait race.)
template <int N>
static __device__ __forceinline__ void vm_wait() {
    static_assert(N == 0 || N == 2 || N == 3 || N == 4 || N == 6 || N == 8,
                  "vm_wait<N>: N not in emitted set");
    if constexpr (N == 0)      asm volatile("s_waitcnt vmcnt(0)" ::: "memory");
    else if constexpr (N == 2) asm volatile("s_waitcnt vmcnt(2)" ::: "memory");
    else if constexpr (N == 3) asm volatile("s_waitcnt vmcnt(3)" ::: "memory");
    else if constexpr (N == 4) asm volatile("s_waitcnt vmcnt(4)" ::: "memory");
    else if constexpr (N == 6) asm volatile("s_waitcnt vmcnt(6)" ::: "memory");
    else if constexpr (N == 8) asm volatile("s_waitcnt vmcnt(8)" ::: "memory");
}
static __device__ __forceinline__ void raw_barrier() {
    asm volatile("s_barrier" ::: "memory");
}
static __device__ __forceinline__ void lgkm0() {
    asm volatile("s_waitcnt lgkmcnt(0)" ::: "memory");
}

// ---------------------------------------------------------------------------
// K_prep: z=0: Wk -> WTk [N][K] bf16; z=1: Wq -> WTq; z=2: wv_sum[i]=sum Wv[i][:]
// ---------------------------------------------------------------------------
__global__ __launch_bounds__(256) void k_prep(const float* __restrict__ Wk,
                                              const float* __restrict__ Wq,
                                              const float* __restrict__ Wv,
                                              ushort* __restrict__ WTk,
                                              ushort* __restrict__ WTq,
                                              float* __restrict__ wv_sum) {
    const int tid = threadIdx.x;
    if (blockIdx.z == 2) {
        __shared__ float red[4];
        const int i = blockIdx.y * 32 + blockIdx.x;
        const float* row = Wv + (size_t)i * D_DIM;
        float p = 0.f;
        for (int c = tid; c < D_DIM; c += 256) p += row[c];
        for (int o = 32; o; o >>= 1) p += __shfl_down(p, o);
        if ((tid & 63) == 0) red[tid >> 6] = p;
        __syncthreads();
        if (tid == 0) wv_sum[i] = red[0] + red[1] + red[2] + red[3];
        return;
    }
    const float* W = (blockIdx.z == 0) ? Wk : Wq;
    ushort* WT     = (blockIdx.z == 0) ? WTk : WTq;
    __shared__ float tile[32][33];          // [k][n]
    const int tx = tid & 31, ty = tid >> 5; // 32 x 8
    const int kb = blockIdx.x * 32, nb = blockIdx.y * 32;
    #pragma unroll
    for (int r = 0; r < 4; ++r)
        tile[ty + 8 * r][tx] = W[(size_t)(kb + ty + 8 * r) * 1024 + nb + tx];
    __syncthreads();
    #pragma unroll
    for (int r = 0; r < 4; ++r)
        WT[(size_t)(nb + ty + 8 * r) * 1024 + kb + tx] =
            f2bs(tile[tx][ty + 8 * r]);
}

// ---------------------------------------------------------------------------
// K1: per t: vsum[b] = x[b,t,:].wv_sum;  y[t,i] = sum_b x[b,t,i]*vsum[b]
// Emits bf16 ROW-MAJOR: yb [T,D], xb [B*T,D]. Vectorized loads/stores.
// ---------------------------------------------------------------------------
__global__ __launch_bounds__(256) void k_vsum_y(const float* __restrict__ x,
                                                const float* __restrict__ wv_sum,
                                                ushort* __restrict__ yb,
                                                ushort* __restrict__ xb) {
    __shared__ float xs[4][D_DIM];
    __shared__ float red[4][4];   // [wave][b]
    const int t = blockIdx.x;
    const int tid = threadIdx.x;
    const int lane = tid & 63, wv = tid >> 6;

    #pragma unroll
    for (int b = 0; b < 4; ++b) {
        const float4* xr = (const float4*)(x + ((size_t)b * T_DIM + t) * D_DIM);
        *(float4*)&xs[b][tid * 4] = xr[tid];
    }
    __syncthreads();

    #pragma unroll
    for (int b = 0; b < 4; ++b) {
        float p = 0.f;
        for (int c = tid; c < D_DIM; c += 256) p += xs[b][c] * wv_sum[c];
        for (int o = 32; o; o >>= 1) p += __shfl_down(p, o);
        if (lane == 0) red[wv][b] = p;
    }
    __syncthreads();

    float vs[4];
    #pragma unroll
    for (int b = 0; b < 4; ++b)
        vs[b] = red[0][b] + red[1][b] + red[2][b] + red[3][b];

    if (tid < 128) {                       // y row t: 128 groups of 8
        const int i0 = tid * 8;
        ushortx8 yv;
        #pragma unroll
        for (int j = 0; j < 8; ++j) {
            float a = 0.f;
            #pragma unroll
            for (int b = 0; b < 4; ++b) a += xs[b][i0 + j] * vs[b];
            yv[j] = f2bs(a);
        }
        *(ushortx8*)(yb + (size_t)t * D_DIM + i0) = yv;
    }
    for (int g = tid; g < 512; g += 256) { // xb rows b*T+t
        const int b = g >> 7, i0 = (g & 127) * 8;
        ushortx8 xv;
        #pragma unroll
        for (int j = 0; j < 8; ++j) xv[j] = f2bs(xs[b][i0 + j]);
        *(ushortx8*)(xb + ((size_t)b * T_DIM + t) * D_DIM + i0) = xv;
    }
}

// ---------------------------------------------------------------------------
// K3a (m-GEMM): 512 threads = 8 waves (4x2), BK=64, dbuf + counted vmcnt,
// XOR swizzle both sides. LOADS=3 here -> vm_wait<3> (now fail-closed).
// ---------------------------------------------------------------------------
template <int MF, int NF>
__global__ __launch_bounds__(512, 4) void k_gemm(const ushort* __restrict__ A,
                                                 const ushort* __restrict__ BT,
                                                 float* __restrict__ C) {
    constexpr int BM = 4 * MF * 16;
    constexpr int BN = 2 * NF * 16;
    constexpr int LOADS = BM / 64 + BN / 64;
    __shared__ ushort As[2][BM][64];
    __shared__ ushort Bs[2][BN][64];
    const int tid = threadIdx.x;
    const int lane = tid & 63, wid = tid >> 6;
    const int wr = wid >> 1, wc = wid & 1;
    const int rowBase = blockIdx.x * BM;
    const int colBase = blockIdx.y * BN;

    f32x4 acc[MF][NF];
    #pragma unroll
    for (int i = 0; i < MF; ++i)
        #pragma unroll
        for (int j = 0; j < NF; ++j) acc[i][j] = f32x4{0.f, 0.f, 0.f, 0.f};

    auto stage = [&](int buf, int kb) {
        #pragma unroll
        for (int q = 0; q < BM / 64; ++q) {
            const int s = q * 8192 + tid * 16;
            const int r = s >> 7, grp = (s >> 4) & 7;
            const int gcol = kb + (((grp ^ (r & 7)) & 7) << 3);
            __builtin_amdgcn_global_load_lds(
                (const AS1 void*)(A + (size_t)(rowBase + r) * 1024 + gcol),
                (AS3 void*)((AS3 char*)&As[buf][0][0] + s), 16, 0, 0);
        }
        #pragma unroll
        for (int q = 0; q < BN / 64; ++q) {
            const int s = q * 8192 + tid * 16;
            const int r = s >> 7, grp = (s >> 4) & 7;
            const int gcol = kb + (((grp ^ (r & 7)) & 7) << 3);
            __builtin_amdgcn_global_load_lds(
                (const AS1 void*)(BT + (size_t)(colBase + r) * 1024 + gcol),
                (AS3 void*)((AS3 char*)&Bs[buf][0][0] + s), 16, 0, 0);
        }
    };

    stage(0, 0);

    #pragma unroll 2
    for (int kt = 0; kt < 16; ++kt) {
        const int cur = kt & 1;
        if (kt < 15) {
            stage(cur ^ 1, (kt + 1) * 64);
            vm_wait<LOADS>();
        } else {
            vm_wait<0>();
        }
        raw_barrier();

        bf16x8 af[2][MF], bfv[2][NF];
        #pragma unroll
        for (int ks = 0; ks < 2; ++ks) {
            const int kg = ks * 4 + (lane >> 4);
            #pragma unroll
            for (int mi = 0; mi < MF; ++mi) {
                const int r = wr * (MF * 16) + mi * 16 + (lane & 15);
                af[ks][mi] = *(const bf16x8*)((const char*)&As[cur][0][0] +
                                              r * 128 + (((kg ^ (r & 7)) & 7) << 4));
            }
            #pragma unroll
            for (int ni = 0; ni < NF; ++ni) {
                const int r = wc * (NF * 16) + ni * 16 + (lane & 15);
                bfv[ks][ni] = *(const bf16x8*)((const char*)&Bs[cur][0][0] +
                                               r * 128 + (((kg ^ (r & 7)) & 7) << 4));
            }
        }
        #pragma unroll
        for (int ks = 0; ks < 2; ++ks)
            #pragma unroll
            for (int mi = 0; mi < MF; ++mi)
                #pragma unroll
                for (int ni = 0; ni < NF; ++ni)
                    acc[mi][ni] = __builtin_amdgcn_mfma_f32_16x16x32_bf16(
                        af[ks][mi], bfv[ks][ni], acc[mi][ni], 0, 0, 0);

        lgkm0();
        raw_barrier();
    }

    #pragma unroll
    for (int mi = 0; mi < MF; ++mi) {
        #pragma unroll
        for (int ni = 0; ni < NF; ++ni) {
            const int col = colBase + wc * (NF * 16) + ni * 16 + (lane & 15);
            #pragma unroll
            for (int q = 0; q < 4; ++q) {
                const int row = rowBase + wr * (MF * 16) + mi * 16 + (lane >> 4) * 4 + q;
                C[(size_t)row * D_DIM + col] = acc[mi][ni][q];
            }
        }
    }
}

// ---------------------------------------------------------------------------
// K3b (Q-GEMM): phase-split deep pipeline. Tile 256x128, BK=64, 8 waves
// (4M x 2N, per-wave 64x64 = 4x4 frags). THREE LDS buffers (144 KB) ->
// prefetch depth 2. Per K-tile, 3 phases of {ds_read subtile | stage-issue
// -> bar -> lgkm0 -> setprio(1) MFMA setprio(0) -> bar}; ONE counted
// vmcnt(6) per K-tile (0 only at the kt=14 drain). Loads span 2 tiles of
// compute. XOR-swizzle both sides. EPI: out = acc * S2[row&2047][col].
// ---------------------------------------------------------------------------
template <int EPI>
__global__ __launch_bounds__(512, 2) void k_gemm8(const ushort* __restrict__ A,
                                                  const ushort* __restrict__ BT,
                                                  float* __restrict__ C,
                                                  const float* __restrict__ S2) {
    constexpr int ABYTES = 256 * 64 * 2;         // 32 KB
    constexpr int BBYTES = 128 * 64 * 2;         // 16 KB
    constexpr int TBYTES = ABYTES + BBYTES;      // 48 KB
    __shared__ char lds[3 * TBYTES];             // 144 KB
    const int tid = threadIdx.x;
    const int lane = tid & 63, wid = tid >> 6;   // 8 waves
    const int wr = wid >> 1, wc = wid & 1;       // 4 x 2
    const int rowBase = blockIdx.x * 256;
    const int colBase = blockIdx.y * 128;

    f32x4 acc[4][4];
    #pragma unroll
    for (int i = 0; i < 4; ++i)
        #pragma unroll
        for (int j = 0; j < 4; ++j) acc[i][j] = f32x4{0.f, 0.f, 0.f, 0.f};

    // stage part p of a K-tile: p=0 -> A rows 0..127 + B rows 0..63;
    //                           p=1 -> A rows 128..255 + B rows 64..127.
    auto stage_part = [&](int buf, int kb, int p) {
        #pragma unroll
        for (int qq = 0; qq < 2; ++qq) {
            const int s = (p * 2 + qq) * 8192 + tid * 16;
            const int r = s >> 7, grp = (s >> 4) & 7;
            const int gcol = kb + (((grp ^ (r & 7)) & 7) << 3);
            __builtin_amdgcn_global_load_lds(
                (const AS1 void*)(A + (size_t)(rowBase + r) * 1024 + gcol),
                (AS3 void*)((AS3 char*)lds + buf * TBYTES + s), 16, 0, 0);
        }
        {
            const int s = p * 8192 + tid * 16;
            const int r = s >> 7, grp = (s >> 4) & 7;
            const int gcol = kb + (((grp ^ (r & 7)) & 7) << 3);
            __builtin_amdgcn_global_load_lds(
                (const AS1 void*)(BT + (size_t)(colBase + r) * 1024 + gcol),
                (AS3 void*)((AS3 char*)lds + buf * TBYTES + ABYTES + s), 16, 0, 0);
        }
    };

    auto rdA = [&](int buf, int mi, int kg) -> bf16x8 {
        const int r = wr * 64 + mi * 16 + (lane & 15);
        return *(const bf16x8*)((const char*)lds + buf * TBYTES +
                                r * 128 + (((kg ^ (r & 7)) & 7) << 4));
    };
    auto rdB = [&](int buf, int ni, int kg) -> bf16x8 {
        const int r = wc * 64 + ni * 16 + (lane & 15);
        return *(const bf16x8*)((const char*)lds + buf * TBYTES + ABYTES +
                                r * 128 + (((kg ^ (r & 7)) & 7) << 4));
    };

    // prologue: tiles 0 and 1 in flight; wait tile 0 (6 left = tile 1's)
    stage_part(0, 0, 0);  stage_part(0, 0, 1);
    stage_part(1, 64, 0); stage_part(1, 64, 1);
    vm_wait<6>();
    raw_barrier();

    const int kg0 = (lane >> 4);
    const int kg1 = 4 + (lane >> 4);
    int cur = 0;

    #pragma unroll 1
    for (int kt = 0; kt < 16; ++kt) {
        int b2 = cur + 2; if (b2 >= 3) b2 -= 3;
        const int kb2 = (kt + 2) * 64;

        bf16x8 af[2][4], bfv[2][4];

        // ---------------- P0
        af[0][0] = rdA(cur, 0, kg0); af[0][1] = rdA(cur, 1, kg0);
        af[1][0] = rdA(cur, 0, kg1); af[1][1] = rdA(cur, 1, kg1);
        bfv[0][0] = rdB(cur, 0, kg0); bfv[0][1] = rdB(cur, 1, kg0);
        bfv[1][0] = rdB(cur, 0, kg1); bfv[1][1] = rdB(cur, 1, kg1);
        if (kt < 14) stage_part(b2, kb2, 0);
        raw_barrier();
        lgkm0();
        __builtin_amdgcn_s_setprio(1);
        #pragma unroll
        for (int ks = 0; ks < 2; ++ks)
            #pragma unroll
            for (int mi = 0; mi < 2; ++mi)
                #pragma unroll
                for (int ni = 0; ni < 2; ++ni)
                    acc[mi][ni] = __builtin_amdgcn_mfma_f32_16x16x32_bf16(
                        af[ks][mi], bfv[ks][ni], acc[mi][ni], 0, 0, 0);
        __builtin_amdgcn_s_setprio(0);
        raw_barrier();

        // ---------------- P1
        bfv[0][2] = rdB(cur, 2, kg0); bfv[0][3] = rdB(cur, 3, kg0);
        bfv[1][2] = rdB(cur, 2, kg1); bfv[1][3] = rdB(cur, 3, kg1);
        if (kt < 14) stage_part(b2, kb2, 1);
        raw_barrier();
        lgkm0();
        __builtin_amdgcn_s_setprio(1);
        #pragma unroll
        for (int ks = 0; ks < 2; ++ks)
            #pragma unroll
            for (int mi = 0; mi < 2; ++mi)
                #pragma unroll
                for (int ni = 2; ni < 4; ++ni)
                    acc[mi][ni] = __builtin_amdgcn_mfma_f32_16x16x32_bf16(
                        af[ks][mi], bfv[ks][ni], acc[mi][ni], 0, 0, 0);
        __builtin_amdgcn_s_setprio(0);
        raw_barrier();

        // ---------------- P2
        af[0][2] = rdA(cur, 2, kg0); af[0][3] = rdA(cur, 3, kg0);
        af[1][2] = rdA(cur, 2, kg1); af[1][3] = rdA(cur, 3, kg1);
        raw_barrier();
        lgkm0();
        __builtin_amdgcn_s_setprio(1);
        #pragma unroll
        for (int ks = 0; ks < 2; ++ks)
            #pragma unroll
            for (int mi = 2; mi < 4; ++mi)
                #pragma unroll
                for (int ni = 0; ni < 4; ++ni)
                    acc[mi][ni] = __builtin_amdgcn_mfma_f32_16x16x32_bf16(
                        af[ks][mi], bfv[ks][ni], acc[mi][ni], 0, 0, 0);
        __builtin_amdgcn_s_setprio(0);
        if (kt < 14)       vm_wait<6>();   // next tile ready; 6 stay in flight
        else if (kt == 14) vm_wait<0>();   // epilogue drain
        raw_barrier();

        cur += 1; if (cur == 3) cur = 0;
    }

    #pragma unroll
    for (int mi = 0; mi < 4; ++mi) {
        #pragma unroll
        for (int ni = 0; ni < 4; ++ni) {
            const int col = colBase + wc * 64 + ni * 16 + (lane & 15);
            #pragma unroll
            for (int q = 0; q < 4; ++q) {
                const int row = rowBase + wr * 64 + mi * 16 + (lane >> 4) * 4 + q;
                float v = acc[mi][ni][q];
                if (EPI)
                    v *= S2[(size_t)(row & (T_DIM - 1)) * D_DIM + col];
                C[(size_t)row * D_DIM + col] = v;
            }
        }
    }
}

// ---------------------------------------------------------------------------
// Parallel scan over t: S[t] = g*S[t-1] + m[t], m[0]:=0, then S[0]=S[1].
// scan2 writes SCRAMBLED: S2[(t&1)*1024 + col][t>>1] = S[t][col].
// ---------------------------------------------------------------------------
#define SC_L 32
#define SC_NC 64

__global__ __launch_bounds__(256) void k_scan1(const float* __restrict__ m,
                                               float* __restrict__ tot) {
    const int col = blockIdx.x * 64 + (threadIdx.x & 63);
    const int ch  = blockIdx.y * 4 + (threadIdx.x >> 6);
    const int t0 = ch * SC_L;
    float r = 0.f;
    #pragma unroll 4
    for (int k = 0; k < SC_L; ++k) {
        const int t = t0 + k;
        const float a = (t == 0) ? 0.f : m[(size_t)t * D_DIM + col];
        r = GAMMA_F * r + a;
    }
    tot[(size_t)ch * D_DIM + col] = r;
}

__global__ __launch_bounds__(256) void k_scan2(const float* __restrict__ m,
                                               const float* __restrict__ tot,
                                               float* __restrict__ S2) {
    __shared__ float ls[128][65];
    const int tid = threadIdx.x;
    const int cl = tid & 63;
    const int ch = tid >> 6;              // 0..3 (local chunk)
    const int col = blockIdx.x * 64 + cl;
    const int chg = blockIdx.y * 4 + ch;  // global chunk
    const int t0 = chg * SC_L;

    float gL = 1.f;
    #pragma unroll
    for (int i = 0; i < SC_L; ++i) gL *= GAMMA_F;

    float carry = 0.f, f = 1.f;    // carry = sum_{j<chg} (g^L)^(chg-1-j) tot[j]
    for (int j = chg - 1; j >= 0; --j) {
        carry += f * tot[(size_t)j * D_DIM + col];
        f *= gL;
    }

    float r = carry, s1 = 0.f;
    #pragma unroll 4
    for (int k = 0; k < SC_L; ++k) {
        const int t = t0 + k;
        const float a = (t == 0) ? 0.f : m[(size_t)t * D_DIM + col];
        r = GAMMA_F * r + a;
        ls[ch * SC_L + k][cl] = r;
        if (t == 1) s1 = r;
    }
    if (blockIdx.y == 0 && ch == 0) ls[0][cl] = s1;   // S[0] = S[1]
    __syncthreads();

    const int c0 = blockIdx.x * 64;
    const int tB = blockIdx.y * 128;
    for (int e = tid; e < 128 * 64; e += 256) {
        const int rr = e >> 6;            // 0..127
        const int j  = e & 63;
        const int hi = rr >> 6, cl2 = rr & 63;
        S2[(size_t)((hi << 10) + c0 + cl2) * D_DIM + (tB >> 1) + j] =
            ls[2 * j + hi][cl2];
    }
}

// ---------------------------------------------------------------------------
extern "C" void kernel_launch(void* const* d_in, const int* in_sizes, int n_in,
                              void* d_out, int out_size, void* d_ws, size_t ws_size,
                              hipStream_t stream) {
    const float* x  = (const float*)d_in[0];   // [4,2048,1024]
    const float* Wq = (const float*)d_in[1];
    const float* Wk = (const float*)d_in[2];
    const float* Wv = (const float*)d_in[3];
    float* out = (float*)d_out;                // [4,2048,1024] fp32
    char* ws = (char*)d_ws;

    // ws layout (40 MB):
    ushort* xb  = (ushort*)(ws);                    // 16 MB  [B*T,D] bf16
    float*  m   = (float*)(ws + (16u << 20));       //  8 MB  [T,D] fp32
    ushort* yb  = (ushort*)(ws + (24u << 20));      //  4 MB  [T,D] bf16
    ushort* WTk = (ushort*)(ws + (28u << 20));      //  2 MB
    ushort* WTq = (ushort*)(ws + (30u << 20));      //  2 MB
    float*  S2  = (float*)(ws + (32u << 20));       //  8 MB  scrambled S
    float*  wv_sum = m;                 // m row 0: never read by scans
    float*  tot = (float*)yb;           // yb consumed by gemm<0> before scans

    dim3 gP(32, 32, 3);
    k_prep<<<gP, 256, 0, stream>>>(Wk, Wq, Wv, WTk, WTq, wv_sum);

    k_vsum_y<<<T_DIM, 256, 0, stream>>>(x, wv_sum, (ushort*)yb, (ushort*)xb);

    // m = y @ Wk : tile 128x64, grid (16,16) = 256 blocks, 8 waves each
    dim3 gm(T_DIM / 128, D_DIM / 64);
    k_gemm<2, 2><<<gm, 512, 0, stream>>>(yb, WTk, m);

    dim3 gs(D_DIM / 64, SC_NC / 4);
    k_scan1<<<gs, 256, 0, stream>>>(m, tot);
    k_scan2<<<gs, 256, 0, stream>>>(m, tot, S2);

    // out = S2 ⊙ (x @ Wq) : tile 256x128, grid (32,8) = 256 blocks, 8 waves
    dim3 gq((4 * T_DIM) / 256, D_DIM / 128);
    k_gemm8<1><<<gq, 512, 0, stream>>>(xb, WTq, out, S2);
}